// Round 13
// baseline (13.912 us; speedup 1.0000x reference)
//
#include <hip/hip_runtime.h>
#include <math.h>

#define HDIM 512
#define LDIM 256
#define G 8     // l-groups (gather split), 32 rows each
#define P 32    // t-row chunks of 16 rows; node-1 grid = G*P = 256 blocks

__device__ __forceinline__ float dot4(const float4& a, const float4& b) {
    return a.x * b.x + a.y * b.y + a.z * b.z + a.w * b.w;
}

// Node 1: 256 blocks x 256 threads (1 block/CU). Block (g,p):
//  - W_th rows for the t-phase prefetched FIRST (latency hides under gather)
//  - loc + blend inputs read via UNIFORM scalar loads (no LDS, no barrier)
//  - single-pass gather: thread owns 2 cols, sums all 32 rows (32-deep ILP)
//  - ONE __syncthreads, then 16 partial-t rows -> tpart[g] (disjoint rows)
__global__ void __launch_bounds__(256)
k_part(const float* __restrict__ td_u, const float* __restrict__ td_l,
       const float* __restrict__ ld_u, const float* __restrict__ ld_l,
       const float* __restrict__ table, const int* __restrict__ loc,
       const float* __restrict__ W_thU, const float* __restrict__ W_thL,
       float* __restrict__ tpart /* [G][2*HDIM] */) {
    __shared__ float s_sm[4 * HDIM];    // 8 KB
    const int tid  = threadIdx.x;
    const int wave = tid >> 6;
    const int lane = tid & 63;
    const int g    = blockIdx.x & (G - 1);
    const int p    = blockIdx.x >> 3;
    const int lbase = g * 32;

    // ---- prefetch this wave's 4 W_th rows (independent of gather) ----
    const int r0 = p * 16 + wave * 4;
    float4 WU[4][2], WL[4][2];
#pragma unroll
    for (int q = 0; q < 4; ++q) {
        const size_t row = (size_t)(r0 + q) * HDIM;
#pragma unroll
        for (int it = 0; it < 2; ++it) {
            const int j = it * 256 + lane * 4;
            WU[q][it] = *(const float4*)(W_thU + row + j);
            WL[q][it] = *(const float4*)(W_thL + row + j);
        }
    }

    // ---- gather: thread owns cols (2*tid, 2*tid+1); sums all 32 rows ----
    {
        const int c2 = tid * 2;
        float2 a0 = {0,0}, a1 = {0,0}, a2 = {0,0}, a3 = {0,0};
#pragma unroll
        for (int half = 0; half < 2; ++half) {
            const int kb = lbase + half * 16;
            // uniform scalar loads (s_load): indices + blend inputs
            int   il[16];
            float wx[16], wy[16], wz[16], ww[16];
#pragma unroll
            for (int k = 0; k < 16; ++k) {
                const int l = kb + k;
                il[k] = loc[l];
                const float a1s = td_u[l], b1s = td_l[l];
                const float beta = a1s / (a1s + b1s);
                const float a2s = ld_u[l], b2s = ld_l[l];
                const float alpha = a2s / (a2s + b2s);
                wx[k] = alpha * beta;
                wy[k] = alpha * (1.0f - beta);
                wz[k] = (1.0f - alpha) * beta;
                ww[k] = (1.0f - alpha) * (1.0f - beta);
            }
            float2 e[16];
#pragma unroll
            for (int k = 0; k < 16; ++k)
                e[k] = *(const float2*)(table + (size_t)il[k] * HDIM + c2);
#pragma unroll
            for (int k = 0; k < 16; ++k) {
                a0.x += wx[k] * e[k].x; a0.y += wx[k] * e[k].y;
                a1.x += wy[k] * e[k].x; a1.y += wy[k] * e[k].y;
                a2.x += wz[k] * e[k].x; a2.y += wz[k] * e[k].y;
                a3.x += ww[k] * e[k].x; a3.y += ww[k] * e[k].y;
            }
        }
        *(float2*)(&s_sm[0 * HDIM + c2]) = a0;
        *(float2*)(&s_sm[1 * HDIM + c2]) = a1;
        *(float2*)(&s_sm[2 * HDIM + c2]) = a2;
        *(float2*)(&s_sm[3 * HDIM + c2]) = a3;
    }
    __syncthreads();

    // ---- partial t: 4 rows per wave, write tpart[g] ----
    {
        float4 S1[2], S2[2], S3[2], S4[2];
#pragma unroll
        for (int it = 0; it < 2; ++it) {
            const int j = it * 256 + lane * 4;
            S1[it] = *(const float4*)(s_sm + 0 * HDIM + j);
            S2[it] = *(const float4*)(s_sm + 1 * HDIM + j);
            S3[it] = *(const float4*)(s_sm + 2 * HDIM + j);
            S4[it] = *(const float4*)(s_sm + 3 * HDIM + j);
        }
        float* tp = tpart + (size_t)g * (2 * HDIM);
#pragma unroll
        for (int q = 0; q < 4; ++q) {
            float pu = 0.f, pl = 0.f;
#pragma unroll
            for (int it = 0; it < 2; ++it) {
                pu += dot4(WU[q][it], S1[it]) + dot4(WL[q][it], S2[it]);
                pl += dot4(WU[q][it], S3[it]) + dot4(WL[q][it], S4[it]);
            }
#pragma unroll
            for (int off = 32; off; off >>= 1) {
                pu += __shfl_down(pu, off);
                pl += __shfl_down(pl, off);
            }
            if (lane == 0) { tp[r0 + q] = pu; tp[HDIM + r0 + q] = pl; }
        }
    }
}

// Node 2: 128 blocks x 256 threads. W loads issued first; reduce G=8
// t-partials (32 KB) into LDS; 4 output rows per block (1 per wave).
__global__ void __launch_bounds__(256)
k_out2(const float* __restrict__ WshU, const float* __restrict__ WshL,
       const float* __restrict__ Wih, const float* __restrict__ tpart,
       const float* __restrict__ hx, float* __restrict__ out) {
    __shared__ float t_comb[2 * HDIM];
    const int tid  = threadIdx.x;
    const int wave = tid >> 6;
    const int lane = tid & 63;
    const int i = blockIdx.x * 4 + wave;

    // issue independent loads first
    float4 WU[2], WL[2], WI[2], HV[2];
    {
        const size_t row = (size_t)i * HDIM;
#pragma unroll
        for (int it = 0; it < 2; ++it) {
            const int j = it * 256 + lane * 4;
            WU[it] = *(const float4*)(WshU + row + j);
            WL[it] = *(const float4*)(WshL + row + j);
            WI[it] = *(const float4*)(Wih + row + j);
            HV[it] = *(const float4*)(hx + j);
        }
    }

    // reduce 8 partials: thread owns float4 slot tid*4 of the 1024-vector
    {
        float4 r = {0, 0, 0, 0};
#pragma unroll
        for (int pgi = 0; pgi < G; ++pgi) {
            const float4 v = *(const float4*)(tpart + (size_t)pgi * (2 * HDIM) + tid * 4);
            r.x += v.x; r.y += v.y; r.z += v.z; r.w += v.w;
        }
        *(float4*)&t_comb[tid * 4] = r;
    }
    __syncthreads();

    float pacc = 0.f;
#pragma unroll
    for (int it = 0; it < 2; ++it) {
        const int j = it * 256 + lane * 4;
        const float4 tu = *(const float4*)(t_comb + j);
        const float4 tl = *(const float4*)(t_comb + HDIM + j);
        pacc += dot4(WU[it], tu) + dot4(WL[it], tl) + dot4(WI[it], HV[it]);
    }
#pragma unroll
    for (int off = 32; off; off >>= 1) pacc += __shfl_down(pacc, off);
    if (lane == 0) out[i] = 1.0f / (1.0f + expf(-pacc));
}

extern "C" void kernel_launch(void* const* d_in, const int* in_sizes, int n_in,
                              void* d_out, int out_size, void* d_ws, size_t ws_size,
                              hipStream_t stream) {
    const float* td_u  = (const float*)d_in[0];
    const float* td_l  = (const float*)d_in[1];
    const float* ld_u  = (const float*)d_in[2];
    const float* ld_l  = (const float*)d_in[3];
    const float* hx    = (const float*)d_in[4];
    const float* W_ih  = (const float*)d_in[5];
    const float* W_thU = (const float*)d_in[6];
    const float* W_thL = (const float*)d_in[7];
    const float* W_shU = (const float*)d_in[8];
    const float* W_shL = (const float*)d_in[9];
    const float* table = (const float*)d_in[10];
    const int*   loc   = (const int*)d_in[11];

    float* tpart = (float*)d_ws;   // G * 2*HDIM floats, fully rewritten each call
    float* out   = (float*)d_out;

    k_part<<<G * P, 256, 0, stream>>>(td_u, td_l, ld_u, ld_l, table, loc,
                                      W_thU, W_thL, tpart);
    k_out2<<<HDIM / 4, 256, 0, stream>>>(W_shU, W_shL, W_ih, tpart, hx, out);
}

// Round 14
// 12.012 us; speedup vs baseline: 1.1582x; 1.1582x over previous
//
#include <hip/hip_runtime.h>
#include <math.h>

#define HDIM 512
#define LDIM 256
#define G 4     // l-groups (gather split)
#define P 32    // t-row chunks
// node-1 grid = G*P = 128 blocks; block b: g = b&3 (64 table rows), p = b>>2 (16 t-rows)

__device__ __forceinline__ void fma4(float4& a, float w, const float4& e) {
    a.x += w * e.x; a.y += w * e.y; a.z += w * e.z; a.w += w * e.w;
}
__device__ __forceinline__ float dot4(const float4& a, const float4& b) {
    return a.x * b.x + a.y * b.y + a.z * b.z + a.w * b.w;
}

// Node 1: 128 blocks x 256 threads. Block (g,p): partial-s over l-group g
// (64 rows, full-row coalesced gather), then 16 partial-t rows (chunk p)
// -> tpart[g][1024] (disjoint rows, no atomics, fully rewritten).
__global__ void __launch_bounds__(256)
k_part(const float* __restrict__ td_u, const float* __restrict__ td_l,
       const float* __restrict__ ld_u, const float* __restrict__ ld_l,
       const float* __restrict__ table, const int* __restrict__ loc,
       const float* __restrict__ W_thU, const float* __restrict__ W_thL,
       float* __restrict__ tpart /* [G][2*HDIM] */) {
    __shared__ float4 w_s[64];           // 1 KB
    __shared__ int    loc_s[64];
    __shared__ float  part[2][4 * HDIM]; // 16 KB
    __shared__ float  s_sm[4 * HDIM];    // 8 KB
    const int tid  = threadIdx.x;
    const int wave = tid >> 6;
    const int lane = tid & 63;
    const int g    = blockIdx.x & (G - 1);
    const int p    = blockIdx.x >> 2;
    const int lbase = g * 64;

    // ---- issue W_th row loads FIRST (independent of gather; hides latency) --
    const int r0 = p * 16 + wave * 4;    // this wave's 4 t-rows
    float4 WU[4][2], WL[4][2];
#pragma unroll
    for (int q = 0; q < 4; ++q) {
        const size_t row = (size_t)(r0 + q) * HDIM;
#pragma unroll
        for (int it = 0; it < 2; ++it) {
            const int j = it * 256 + lane * 4;
            WU[q][it] = *(const float4*)(W_thU + row + j);
            WL[q][it] = *(const float4*)(W_thL + row + j);
        }
    }

    // ---- blend weights + indices for this l-group ----
    if (tid < 64) {
        const int l = lbase + tid;
        const float a1 = td_u[l], b1 = td_l[l];
        const float beta = a1 / (a1 + b1);
        const float a2 = ld_u[l], b2 = ld_l[l];
        const float alpha = a2 / (a2 + b2);
        w_s[tid] = make_float4(alpha * beta, alpha * (1.0f - beta),
                               (1.0f - alpha) * beta, (1.0f - alpha) * (1.0f - beta));
        loc_s[tid] = loc[l];
    }
    __syncthreads();

    // ---- gather: half h (tid>>7) sums rows [h*32, h*32+32) of the group ----
    {
        const int h  = tid >> 7;
        const int c  = tid & 127;
        const int h4 = c * 4;
        const int rb = h * 32;
        float4 a0 = {0,0,0,0}, a1v = {0,0,0,0}, a2v = {0,0,0,0}, a3v = {0,0,0,0};
#pragma unroll
        for (int base = 0; base < 32; base += 16) {
            float4 e[16];
#pragma unroll
            for (int k = 0; k < 16; ++k)
                e[k] = *(const float4*)(table + (size_t)loc_s[rb + base + k] * HDIM + h4);
#pragma unroll
            for (int k = 0; k < 16; ++k) {
                const float4 w = w_s[rb + base + k];
                fma4(a0,  w.x, e[k]);
                fma4(a1v, w.y, e[k]);
                fma4(a2v, w.z, e[k]);
                fma4(a3v, w.w, e[k]);
            }
        }
        *(float4*)(&part[h][0 * HDIM + h4]) = a0;
        *(float4*)(&part[h][1 * HDIM + h4]) = a1v;
        *(float4*)(&part[h][2 * HDIM + h4]) = a2v;
        *(float4*)(&part[h][3 * HDIM + h4]) = a3v;
    }
    __syncthreads();

    // ---- reduce 2 halves into s_sm (thread owns 8 consecutive floats) ----
    {
        const int s0 = tid * 8;
        const float4 u0 = *(const float4*)(&part[0][s0]);
        const float4 u1 = *(const float4*)(&part[0][s0 + 4]);
        const float4 v0 = *(const float4*)(&part[1][s0]);
        const float4 v1 = *(const float4*)(&part[1][s0 + 4]);
        *(float4*)(&s_sm[s0])     = make_float4(u0.x + v0.x, u0.y + v0.y, u0.z + v0.z, u0.w + v0.w);
        *(float4*)(&s_sm[s0 + 4]) = make_float4(u1.x + v1.x, u1.y + v1.y, u1.z + v1.z, u1.w + v1.w);
    }
    __syncthreads();

    // ---- partial t: 4 rows per wave (R4 layout), write tpart[g] ----
    {
        float4 S1[2], S2[2], S3[2], S4[2];
#pragma unroll
        for (int it = 0; it < 2; ++it) {
            const int j = it * 256 + lane * 4;
            S1[it] = *(const float4*)(s_sm + 0 * HDIM + j);
            S2[it] = *(const float4*)(s_sm + 1 * HDIM + j);
            S3[it] = *(const float4*)(s_sm + 2 * HDIM + j);
            S4[it] = *(const float4*)(s_sm + 3 * HDIM + j);
        }
        float* tp = tpart + (size_t)g * (2 * HDIM);
#pragma unroll
        for (int q = 0; q < 4; ++q) {
            float pu = 0.f, pl = 0.f;
#pragma unroll
            for (int it = 0; it < 2; ++it) {
                pu += dot4(WU[q][it], S1[it]) + dot4(WL[q][it], S2[it]);
                pl += dot4(WU[q][it], S3[it]) + dot4(WL[q][it], S4[it]);
            }
#pragma unroll
            for (int off = 32; off; off >>= 1) {
                pu += __shfl_down(pu, off);
                pl += __shfl_down(pl, off);
            }
            if (lane == 0) { tp[r0 + q] = pu; tp[HDIM + r0 + q] = pl; }
        }
    }
}

// Node 2: 128 blocks x 256 threads. W loads issued first; reduce G=4
// t-partials (16 KB) into LDS; 4 output rows per block (1 per wave).
__global__ void __launch_bounds__(256)
k_out2(const float* __restrict__ WshU, const float* __restrict__ WshL,
       const float* __restrict__ Wih, const float* __restrict__ tpart,
       const float* __restrict__ hx, float* __restrict__ out) {
    __shared__ float t_comb[2 * HDIM];
    const int tid  = threadIdx.x;
    const int wave = tid >> 6;
    const int lane = tid & 63;
    const int i = blockIdx.x * 4 + wave;

    // issue independent loads first
    float4 WU[2], WL[2], WI[2], HV[2];
    {
        const size_t row = (size_t)i * HDIM;
#pragma unroll
        for (int it = 0; it < 2; ++it) {
            const int j = it * 256 + lane * 4;
            WU[it] = *(const float4*)(WshU + row + j);
            WL[it] = *(const float4*)(WshL + row + j);
            WI[it] = *(const float4*)(Wih + row + j);
            HV[it] = *(const float4*)(hx + j);
        }
    }

    // reduce 4 partials: thread owns float4 slot tid*4 of the 1024-vector
    {
        float4 r = {0, 0, 0, 0};
#pragma unroll
        for (int p = 0; p < G; ++p) {
            const float4 v = *(const float4*)(tpart + (size_t)p * (2 * HDIM) + tid * 4);
            r.x += v.x; r.y += v.y; r.z += v.z; r.w += v.w;
        }
        *(float4*)&t_comb[tid * 4] = r;
    }
    __syncthreads();

    float pacc = 0.f;
#pragma unroll
    for (int it = 0; it < 2; ++it) {
        const int j = it * 256 + lane * 4;
        const float4 tu = *(const float4*)(t_comb + j);
        const float4 tl = *(const float4*)(t_comb + HDIM + j);
        pacc += dot4(WU[it], tu) + dot4(WL[it], tl) + dot4(WI[it], HV[it]);
    }
#pragma unroll
    for (int off = 32; off; off >>= 1) pacc += __shfl_down(pacc, off);
    if (lane == 0) out[i] = 1.0f / (1.0f + expf(-pacc));
}

extern "C" void kernel_launch(void* const* d_in, const int* in_sizes, int n_in,
                              void* d_out, int out_size, void* d_ws, size_t ws_size,
                              hipStream_t stream) {
    const float* td_u  = (const float*)d_in[0];
    const float* td_l  = (const float*)d_in[1];
    const float* ld_u  = (const float*)d_in[2];
    const float* ld_l  = (const float*)d_in[3];
    const float* hx    = (const float*)d_in[4];
    const float* W_ih  = (const float*)d_in[5];
    const float* W_thU = (const float*)d_in[6];
    const float* W_thL = (const float*)d_in[7];
    const float* W_shU = (const float*)d_in[8];
    const float* W_shL = (const float*)d_in[9];
    const float* table = (const float*)d_in[10];
    const int*   loc   = (const int*)d_in[11];

    float* tpart = (float*)d_ws;   // G * 2*HDIM floats, fully rewritten each call
    float* out   = (float*)d_out;

    k_part<<<G * P, 256, 0, stream>>>(td_u, td_l, ld_u, ld_l, table, loc,
                                      W_thU, W_thL, tpart);
    k_out2<<<HDIM / 4, 256, 0, stream>>>(W_shU, W_shL, W_ih, tpart, hx, out);
}